// Round 2
// baseline (217.179 us; speedup 1.0000x reference)
//
#include <hip/hip_runtime.h>
#include <hip/hip_bf16.h>
#include <math.h>

#define BT 128  // threads (=samples) per block

// ---------------- setup kernel: build the fixed variational operator M ----------------
// M is 64x64 complex row-major [j][k] as float2. Column k = gates(e_k).
// One block (=1 wave, 64 lanes) per column; lane r holds amplitude r. Gates via shfl_xor.

__device__ __forceinline__ void rot_gate(float& re, float& im, int r, int bit, float th) {
  float s, c;
  __sincosf(th, &s, &c);
  if ((r >> bit) & 1) {
    float nr = re * c - im * s;
    float ni = re * s + im * c;
    re = nr; im = ni;
  }
}

__device__ __forceinline__ void sq_gate(float& re, float& im, int r, int bit, float rr) {
  float sech = 1.0f / coshf(rr);
  float f0 = sqrtf(sech);
  float f1 = sech * f0;
  float m = ((r >> bit) & 1) ? f1 : f0;
  re *= m; im *= m;
}

__device__ __forceinline__ void disp_gate(float& re, float& im, int r, int bit, float a) {
  // D(a) real a, truncated: pref*[[1,-a],[a,1-a^2]]
  float pref = __expf(-0.5f * a * a);
  float pre = __shfl_xor(re, 1 << bit, 64);
  float pim = __shfl_xor(im, 1 << bit, 64);
  int b = (r >> bit) & 1;
  float A = pref * (b ? (1.0f - a * a) : 1.0f);
  float B = pref * (b ? a : -a);
  re = A * re + B * pre;
  im = A * im + B * pim;
}

__device__ __forceinline__ void bs_gate(float& re, float& im, int r, int bita, int bitb,
                                        float th, float ph) {
  float s, c;  __sincosf(th, &s, &c);
  float sp, cp; __sincosf(ph, &sp, &cp);
  float c2 = c * c - s * s;  // cos(2*theta)
  int na = (r >> bita) & 1;
  int nb = (r >> bitb) & 1;
  int mask = (1 << bita) | (1 << bitb);
  float pre = __shfl_xor(re, mask, 64);
  float pim = __shfl_xor(im, mask, 64);
  float A, Tr, Ti;
  if (na == nb) {
    A = na ? c2 : 1.0f; Tr = 0.0f; Ti = 0.0f;
  } else {
    A = c;
    Tr = na ? (-s * cp) : (s * cp);
    Ti = s * sp;
  }
  float nr = A * re + Tr * pre - Ti * pim;
  float ni = A * im + Tr * pim + Ti * pre;
  re = nr; im = ni;
}

__global__ __launch_bounds__(64) void build_M(const float* __restrict__ var,
                                              float2* __restrict__ M) {
  const int c = blockIdx.x;   // column (input basis state)
  const int r = threadIdx.x;  // row (amplitude index); wire w <-> bit (5-w)
  float re = (r == c) ? 1.0f : 0.0f;
  float im = 0.0f;
  for (int l = 0; l < 2; ++l) {
    const float* v = var + l * 50;
    for (int i = 0; i < 5; ++i) bs_gate(re, im, r, 5 - i, 4 - i, v[2 * i], v[2 * i + 1]);
    for (int w = 0; w < 6; ++w) rot_gate(re, im, r, 5 - w, v[10 + w]);
    for (int w = 0; w < 6; ++w) sq_gate(re, im, r, 5 - w, v[16 + w]);
    for (int i = 0; i < 5; ++i) bs_gate(re, im, r, 5 - i, 4 - i, v[22 + 2 * i], v[23 + 2 * i]);
    for (int w = 0; w < 6; ++w) rot_gate(re, im, r, 5 - w, v[32 + w]);
    for (int w = 0; w < 6; ++w) disp_gate(re, im, r, 5 - w, v[38 + w]);
    for (int w = 0; w < 6; ++w) rot_gate(re, im, r, 5 - w, v[44 + w]);  // Kerr == rot at cutoff 2
  }
  M[r * 64 + c] = make_float2(re, im);
}

// ---------------- main kernel: thread-per-sample ----------------
// amdgpu_waves_per_eu(2,2): LDS already caps occupancy at 4 blocks/CU = 2 waves/EU,
// so tell the register allocator that 2 waves/EU is the target -> budget 256 VGPRs,
// keeping ar[64]/ai[64] fully in registers with ZERO scratch spill (R1 spilled ~120 B/thread
// at the default 4-waves/EU target of 128 VGPRs).

__global__ __launch_bounds__(BT)
__attribute__((amdgpu_waves_per_eu(2, 2)))
void ff_main(const float* __restrict__ x,
             const float* __restrict__ gamma,
             const float* __restrict__ beta,
             const float* __restrict__ Mf,
             float* __restrict__ out) {
  __shared__ float yb[BT * 65];     // x tile, overwritten in-place by y (=probs+x). +1 pad.
  __shared__ float mu_s[BT];
  __shared__ float inv_s[BT];

  const int t = threadIdx.x;
  const size_t base = (size_t)blockIdx.x * (BT * 64);

  // ---- phase 1: coalesced stage of x tile into LDS ----
  {
    const float4* xv = (const float4*)(x + base);
    #pragma unroll
    for (int it = 0; it < 16; ++it) {
      float4 q = xv[it * BT + t];
      int fi = (it * BT + t) * 4;
      int s = fi >> 6;
      int j = fi & 63;
      float* row = &yb[s * 65 + j];
      row[0] = q.x; row[1] = q.y; row[2] = q.z; row[3] = q.w;
    }
  }
  __syncthreads();

  float* xr = &yb[t * 65];  // this thread's sample row

  // ---- phase 2a: per-wire 2-vectors (t0 real, t1 complex) ----
  float t0[6], t1r[6], t1i[6];
  #pragma unroll
  for (int w = 0; w < 6; ++w) {
    float r1  = xr[2 * w];
    float rd  = xr[28 + 2 * w];
    float pd  = xr[29 + 2 * w];
    float kk  = xr[40 + w];
    float r2  = xr[46 + 2 * w];
    float th2 = xr[58 + w];
    float sech1 = 1.0f / coshf(r1);
    float sech2 = 1.0f / coshf(r2);
    float s1h = sqrtf(sech1);
    float s2h = sqrtf(sech2);
    float pref = __expf(-0.5f * rd * rd);
    float c0 = s1h * pref;
    t0[w] = c0 * s2h;
    float m1 = c0 * rd * sech2 * s2h;
    float ph = pd + kk + th2;
    float sp, cp;
    __sincosf(ph, &sp, &cp);
    t1r[w] = m1 * cp;
    t1i[w] = m1 * sp;
  }

  // ---- phase 2b: product state a[64] via tensor doubling (bit p <-> wire 5-p) ----
  float ar[64], ai[64];
  ar[0] = t0[5];  ai[0] = 0.0f;
  ar[1] = t1r[5]; ai[1] = t1i[5];
  #pragma unroll
  for (int p = 1; p < 6; ++p) {
    const int w = 5 - p;
    const int half = 1 << p;
    #pragma unroll
    for (int n = 0; n < half; ++n) {
      float br = ar[n], bi = ai[n];
      ar[n + half] = t1r[w] * br - t1i[w] * bi;
      ai[n + half] = t1r[w] * bi + t1i[w] * br;
      ar[n] = t0[w] * br;
      ai[n] = t0[w] * bi;
    }
  }

  // ---- phase 2c: amp_out = M a ; probs=|amp|^2 ; y = probs + x (in place) ----
  float s1 = 0.0f, s2 = 0.0f;
  #pragma unroll 1
  for (int j = 0; j < 64; ++j) {
    const float4* Mr4 = (const float4*)(Mf + j * 128);  // row j: 64 complex = 32 float4
    float accr0 = 0.0f, acci0 = 0.0f, accr1 = 0.0f, acci1 = 0.0f;
    #pragma unroll
    for (int k2 = 0; k2 < 32; k2 += 2) {
      float4 m0 = Mr4[k2];
      float4 m1 = Mr4[k2 + 1];
      int k = 2 * k2;
      accr0 = fmaf(m0.x, ar[k],     fmaf(-m0.y, ai[k],     accr0));
      acci0 = fmaf(m0.x, ai[k],     fmaf( m0.y, ar[k],     acci0));
      accr0 = fmaf(m0.z, ar[k + 1], fmaf(-m0.w, ai[k + 1], accr0));
      acci0 = fmaf(m0.z, ai[k + 1], fmaf( m0.w, ar[k + 1], acci0));
      accr1 = fmaf(m1.x, ar[k + 2], fmaf(-m1.y, ai[k + 2], accr1));
      acci1 = fmaf(m1.x, ai[k + 2], fmaf( m1.y, ar[k + 2], acci1));
      accr1 = fmaf(m1.z, ar[k + 3], fmaf(-m1.w, ai[k + 3], accr1));
      acci1 = fmaf(m1.z, ai[k + 3], fmaf( m1.w, ar[k + 3], acci1));
    }
    float accr = accr0 + accr1;
    float acci = acci0 + acci1;
    float pj = accr * accr + acci * acci;
    float yj = pj + xr[j];
    xr[j] = yj;
    s1 += yj;
    s2 += yj * yj;
  }

  float mu = s1 * (1.0f / 64.0f);
  float varr = fmaf(s2, 1.0f / 64.0f, -mu * mu);
  mu_s[t] = mu;
  inv_s[t] = rsqrtf(varr + 1e-5f);
  __syncthreads();

  // ---- phase 3: LayerNorm + coalesced float4 store ----
  {
    int j0 = (4 * t) & 63;
    float4 g4 = *(const float4*)(gamma + j0);
    float4 b4 = *(const float4*)(beta + j0);
    float4* ov = (float4*)(out + base);
    #pragma unroll
    for (int it = 0; it < 16; ++it) {
      int fi = (it * BT + t) * 4;
      int s = fi >> 6;
      float m = mu_s[s];
      float iv = inv_s[s];
      const float* row = &yb[s * 65 + j0];
      float4 o;
      o.x = (row[0] - m) * iv * g4.x + b4.x;
      o.y = (row[1] - m) * iv * g4.y + b4.y;
      o.z = (row[2] - m) * iv * g4.z + b4.z;
      o.w = (row[3] - m) * iv * g4.w + b4.w;
      ov[it * BT + t] = o;
    }
  }
}

extern "C" void kernel_launch(void* const* d_in, const int* in_sizes, int n_in,
                              void* d_out, int out_size, void* d_ws, size_t ws_size,
                              hipStream_t stream) {
  const float* x     = (const float*)d_in[0];
  const float* var   = (const float*)d_in[1];
  const float* gamma = (const float*)d_in[2];
  const float* beta  = (const float*)d_in[3];
  float* out = (float*)d_out;
  float2* M = (float2*)d_ws;  // 64*64 complex = 32 KB

  build_M<<<64, 64, 0, stream>>>(var, M);

  int nsamples = in_sizes[0] / 64;        // 131072
  int blocks = nsamples / BT;             // 1024
  ff_main<<<blocks, BT, 0, stream>>>(x, gamma, beta, (const float*)M, out);
}

// Round 3
// 123.619 us; speedup vs baseline: 1.7568x; 1.7568x over previous
//
#include <hip/hip_runtime.h>
#include <hip/hip_bf16.h>
#include <math.h>

typedef _Float16 f16x8 __attribute__((ext_vector_type(8)));
typedef float f32x4 __attribute__((ext_vector_type(4)));

// ---------------- setup kernel 1: build the fixed variational operator M ----------------
// M is 64x64 complex row-major [j][k] as float2. Column k = gates(e_k).
// One block (=1 wave, 64 lanes) per column; lane r holds amplitude r. Gates via shfl_xor.

__device__ __forceinline__ void rot_gate(float& re, float& im, int r, int bit, float th) {
  float s, c;
  __sincosf(th, &s, &c);
  if ((r >> bit) & 1) {
    float nr = re * c - im * s;
    float ni = re * s + im * c;
    re = nr; im = ni;
  }
}

__device__ __forceinline__ void sq_gate(float& re, float& im, int r, int bit, float rr) {
  float sech = 1.0f / coshf(rr);
  float f0 = sqrtf(sech);
  float f1 = sech * f0;
  float m = ((r >> bit) & 1) ? f1 : f0;
  re *= m; im *= m;
}

__device__ __forceinline__ void disp_gate(float& re, float& im, int r, int bit, float a) {
  // D(a) real a, truncated: pref*[[1,-a],[a,1-a^2]]
  float pref = __expf(-0.5f * a * a);
  float pre = __shfl_xor(re, 1 << bit, 64);
  float pim = __shfl_xor(im, 1 << bit, 64);
  int b = (r >> bit) & 1;
  float A = pref * (b ? (1.0f - a * a) : 1.0f);
  float B = pref * (b ? a : -a);
  re = A * re + B * pre;
  im = A * im + B * pim;
}

__device__ __forceinline__ void bs_gate(float& re, float& im, int r, int bita, int bitb,
                                        float th, float ph) {
  float s, c;  __sincosf(th, &s, &c);
  float sp, cp; __sincosf(ph, &sp, &cp);
  float c2 = c * c - s * s;  // cos(2*theta)
  int na = (r >> bita) & 1;
  int nb = (r >> bitb) & 1;
  int mask = (1 << bita) | (1 << bitb);
  float pre = __shfl_xor(re, mask, 64);
  float pim = __shfl_xor(im, mask, 64);
  float A, Tr, Ti;
  if (na == nb) {
    A = na ? c2 : 1.0f; Tr = 0.0f; Ti = 0.0f;
  } else {
    A = c;
    Tr = na ? (-s * cp) : (s * cp);
    Ti = s * sp;
  }
  float nr = A * re + Tr * pre - Ti * pim;
  float ni = A * im + Tr * pim + Ti * pre;
  re = nr; im = ni;
}

__global__ __launch_bounds__(64) void build_M(const float* __restrict__ var,
                                              float2* __restrict__ M) {
  const int c = blockIdx.x;   // column (input basis state)
  const int r = threadIdx.x;  // row (amplitude index); wire w <-> bit (5-w)
  float re = (r == c) ? 1.0f : 0.0f;
  float im = 0.0f;
  for (int l = 0; l < 2; ++l) {
    const float* v = var + l * 50;
    for (int i = 0; i < 5; ++i) bs_gate(re, im, r, 5 - i, 4 - i, v[2 * i], v[2 * i + 1]);
    for (int w = 0; w < 6; ++w) rot_gate(re, im, r, 5 - w, v[10 + w]);
    for (int w = 0; w < 6; ++w) sq_gate(re, im, r, 5 - w, v[16 + w]);
    for (int i = 0; i < 5; ++i) bs_gate(re, im, r, 5 - i, 4 - i, v[22 + 2 * i], v[23 + 2 * i]);
    for (int w = 0; w < 6; ++w) rot_gate(re, im, r, 5 - w, v[32 + w]);
    for (int w = 0; w < 6; ++w) disp_gate(re, im, r, 5 - w, v[38 + w]);
    for (int w = 0; w < 6; ++w) rot_gate(re, im, r, 5 - w, v[44 + w]);  // Kerr == rot at cutoff 2
  }
  M[r * 64 + c] = make_float2(re, im);
}

// ---------------- setup kernel 2: pack W = [Mr -Mi; Mi Mr] into f16 A-fragment order ------
// A-fragment of mfma_f32_16x16x32_f16: lane l holds A[m = l&15][k = (l>>4)*8 + j], j=0..7.
// Packed stream: Wp[((rt*4 + kk)*64 + lane)*8 + j] = W[rt*16 + (lane&15)][kk*32 + (lane>>4)*8 + j]
// -> main kernel reads lane-linear ds_read_b128 (conflict-free).

__global__ __launch_bounds__(256) void pack_W(const float2* __restrict__ M,
                                              _Float16* __restrict__ Wp) {
  int tt = blockIdx.x * 256 + threadIdx.x;  // grid 4 x 256 = 1024
  for (int idx = tt; idx < 2048; idx += 1024) {
    int lane = idx & 63;
    int kk = (idx >> 6) & 3;
    int rt = idx >> 8;
    int m = rt * 16 + (lane & 15);
    int k0 = kk * 32 + (lane >> 4) * 8;
    f16x8 h;
    #pragma unroll
    for (int j = 0; j < 8; ++j) {
      int k = k0 + j;
      float v;
      if (m < 64) {
        v = (k < 64) ? M[m * 64 + k].x : -M[m * 64 + (k - 64)].y;
      } else {
        v = (k < 64) ? M[(m - 64) * 64 + k].y : M[(m - 64) * 64 + (k - 64)].x;
      }
      h[j] = (_Float16)v;
    }
    *(f16x8*)(Wp + (size_t)idx * 8) = h;
  }
}

// ---------------- main kernel: 256 threads = 4 waves, 64 samples per block ----------------
// GEMM formulation: Amp(128 x N) = W(128x128) x V(128 x N), V = [Re a; Im a] per sample.
// 4 threads per sample build the product state straight into B-fragment-packed LDS
// (B-frag: lane l holds B[k=(l>>4)*8+j][n=l&15]); each wave MFMAs 16 samples x 128 rows.
// C/D layout (col=lane&15,row=(lane>>4)*4+reg) puts Re(row-tile rt) and Im(rt+4) of the
// same output element in the same lane -> prob, residual, LN, store all in-register.

__global__ __launch_bounds__(256) void ff_main(const float* __restrict__ x,
                                               const float* __restrict__ gamma,
                                               const float* __restrict__ beta,
                                               const _Float16* __restrict__ Wp,
                                               float* __restrict__ out) {
  __shared__ __align__(16) _Float16 Wl[16384];   // 32 KB packed W fragments
  __shared__ __align__(16) _Float16 Sl[8192];    // 16 KB packed state B-fragments (4 waves)
  __shared__ float xl[64 * 65];                  // 16.6 KB x tile (+1 pad)

  const int t = threadIdx.x;
  const size_t base = (size_t)blockIdx.x * (64 * 64);

  // ---- stage W fragments (32 KB) and x tile (16 KB), coalesced ----
  {
    const float4* src = (const float4*)Wp;
    float4* dst = (float4*)Wl;
    #pragma unroll
    for (int i = 0; i < 8; ++i) dst[i * 256 + t] = src[i * 256 + t];
  }
  {
    const float4* xv = (const float4*)(x + base);
    #pragma unroll
    for (int i = 0; i < 4; ++i) {
      int ci = i * 256 + t;
      float4 q = xv[ci];
      int fi = ci * 4;
      int s = fi >> 6;
      int j = fi & 63;
      float* row = &xl[s * 65 + j];
      row[0] = q.x; row[1] = q.y; row[2] = q.z; row[3] = q.w;
    }
  }
  __syncthreads();

  // ---- state build: thread (s = t>>2, p = t&3) computes a[p*16 .. p*16+15] ----
  {
    const int s = t >> 2, p = t & 3;
    const float* X = &xl[s * 65];

    float t0[6], t1r[6], t1i[6];
    #pragma unroll
    for (int w = 0; w < 6; ++w) {
      float r1  = X[2 * w];
      float rd  = X[28 + 2 * w];
      float pd  = X[29 + 2 * w];
      float kk_ = X[40 + w];
      float r2  = X[46 + 2 * w];
      float th2 = X[58 + w];
      float sech1 = 1.0f / coshf(r1);
      float sech2 = 1.0f / coshf(r2);
      float s1h = sqrtf(sech1);
      float s2h = sqrtf(sech2);
      float pref = __expf(-0.5f * rd * rd);
      float c0 = s1h * pref;
      t0[w] = c0 * s2h;
      float m1 = c0 * rd * sech2 * s2h;
      float ph = pd + kk_ + th2;
      float sp, cp;
      __sincosf(ph, &sp, &cp);
      t1r[w] = m1 * cp;
      t1i[w] = m1 * sp;
    }

    // prefix over wires 0 (bit5 = p>>1) and 1 (bit4 = p&1)
    float pr, pi;
    {
      int b0 = (p >> 1) & 1, b1 = p & 1;
      float a0r = b0 ? t1r[0] : t0[0];
      float a0i = b0 ? t1i[0] : 0.0f;
      float a1r = b1 ? t1r[1] : t0[1];
      float a1i = b1 ? t1i[1] : 0.0f;
      pr = a0r * a1r - a0i * a1i;
      pi = a0r * a1i + a0i * a1r;
    }

    // tensor-double wires 5,4,3,2 into bits 0..3 of the 16-chunk
    float tr[16], ti[16];
    tr[0] = pr; ti[0] = pi;
    #pragma unroll
    for (int st = 0; st < 4; ++st) {
      const int w = 5 - st;
      const int half = 1 << st;
      #pragma unroll
      for (int n = 0; n < half; ++n) {
        float br = tr[n], bi = ti[n];
        tr[n + half] = br * t1r[w] - bi * t1i[w];
        ti[n + half] = br * t1i[w] + bi * t1r[w];
        tr[n] = br * t0[w];
        ti[n] = bi * t0[w];
      }
    }

    // write B-fragment-packed halves: Re rows k=p*16+i (kk=p>>1), Im rows k=64+p*16+i (kk=2+(p>>1))
    const int ws_ = s >> 4, c = s & 15;
    const int kkre = p >> 1;
    #pragma unroll
    for (int j8 = 0; j8 < 2; ++j8) {
      const int q = ((p & 1) << 1) + j8;
      f16x8 hre, him;
      #pragma unroll
      for (int j = 0; j < 8; ++j) {
        hre[j] = (_Float16)tr[j8 * 8 + j];
        him[j] = (_Float16)ti[j8 * 8 + j];
      }
      *(f16x8*)&Sl[(size_t)((ws_ * 4 + kkre) * 64 + q * 16 + c) * 8] = hre;
      *(f16x8*)&Sl[(size_t)((ws_ * 4 + kkre + 2) * 64 + q * 16 + c) * 8] = him;
    }
  }
  __syncthreads();

  // ---- GEMM: wave w -> samples w*16..w*16+15, all 128 output rows ----
  const int w = t >> 6;
  const int lane = t & 63;
  const int q = lane >> 4;
  const int c = lane & 15;

  f32x4 acc[8];
  #pragma unroll
  for (int rt = 0; rt < 8; ++rt) acc[rt] = (f32x4){0.0f, 0.0f, 0.0f, 0.0f};

  #pragma unroll
  for (int kk = 0; kk < 4; ++kk) {
    f16x8 b = *(const f16x8*)&Sl[(size_t)((w * 4 + kk) * 64 + lane) * 8];
    #pragma unroll
    for (int rt = 0; rt < 8; ++rt) {
      f16x8 a = *(const f16x8*)&Wl[(size_t)((rt * 4 + kk) * 64 + lane) * 8];
      acc[rt] = __builtin_amdgcn_mfma_f32_16x16x32_f16(a, b, acc[rt], 0, 0, 0);
    }
  }

  // ---- epilogue: prob = re^2+im^2, residual, LayerNorm (4-lane shuffle reduce), store ----
  const int s = w * 16 + c;
  float y[4][4];
  float s1 = 0.0f, s2 = 0.0f;
  #pragma unroll
  for (int rt = 0; rt < 4; ++rt) {
    #pragma unroll
    for (int reg = 0; reg < 4; ++reg) {
      float re = acc[rt][reg];
      float im = acc[rt + 4][reg];
      int j = rt * 16 + q * 4 + reg;
      float yy = fmaf(re, re, im * im) + xl[s * 65 + j];
      y[rt][reg] = yy;
      s1 += yy;
      s2 += yy * yy;
    }
  }
  s1 += __shfl_xor(s1, 16, 64); s1 += __shfl_xor(s1, 32, 64);
  s2 += __shfl_xor(s2, 16, 64); s2 += __shfl_xor(s2, 32, 64);
  float mu = s1 * (1.0f / 64.0f);
  float inv = rsqrtf(fmaf(s2, 1.0f / 64.0f, -mu * mu) + 1e-5f);

  #pragma unroll
  for (int rt = 0; rt < 4; ++rt) {
    int j0 = rt * 16 + q * 4;
    float4 g = *(const float4*)(gamma + j0);
    float4 bb = *(const float4*)(beta + j0);
    float4 o;
    o.x = (y[rt][0] - mu) * inv * g.x + bb.x;
    o.y = (y[rt][1] - mu) * inv * g.y + bb.y;
    o.z = (y[rt][2] - mu) * inv * g.z + bb.z;
    o.w = (y[rt][3] - mu) * inv * g.w + bb.w;
    *(float4*)(out + base + (size_t)s * 64 + j0) = o;
  }
}

extern "C" void kernel_launch(void* const* d_in, const int* in_sizes, int n_in,
                              void* d_out, int out_size, void* d_ws, size_t ws_size,
                              hipStream_t stream) {
  const float* x     = (const float*)d_in[0];
  const float* var   = (const float*)d_in[1];
  const float* gamma = (const float*)d_in[2];
  const float* beta  = (const float*)d_in[3];
  float* out = (float*)d_out;

  float2* M = (float2*)d_ws;                              // 32 KB
  _Float16* Wp = (_Float16*)((char*)d_ws + 64 * 64 * 8);  // 32 KB packed f16 fragments

  build_M<<<64, 64, 0, stream>>>(var, M);
  pack_W<<<4, 256, 0, stream>>>(M, Wp);

  int nsamples = in_sizes[0] / 64;     // 131072
  int blocks = nsamples / 64;          // 2048
  ff_main<<<blocks, 256, 0, stream>>>(x, gamma, beta, Wp, out);
}